// Round 19
// baseline (266.932 us; speedup 1.0000x reference)
//
#include <hip/hip_runtime.h>
#include <hip/hip_bf16.h>

#define N_NODES 50000
#define E_EDGES 800000
#define ET (E_EDGES + N_NODES)   /* 850000 edges incl self loops */
#define IN_DIM 128
#define HID 96
#define HEADS 2
#define CPH 48
#define NEG_SLOPE 0.2f
#define LN_EPS 1e-5f
#define CHUNK 24                 /* edges per softmax/agg chunk */
#define LROW 50                  /* LDS dwords per staged edge row */
#define PBASE (CHUNK * LROW)
#define WTILE (PBASE + 2 * CHUNK)/* per-wave LDS dwords: 1248 -> 4992 B */
#define FBLK 2048                /* persistent-wave grid for k_node_fused */
#define GBLK ((N_NODES + 63) / 64)
#define WPTOT (IN_DIM * HID)     /* 12288 */
#define WCTOT (HID * 2 * HID)    /* 18432 per layer */
#define XLP 128                  /* padded xl row stride (h16): 256B, line-aligned heads */

typedef __hip_bfloat16 bf16;
typedef short bf16x8 __attribute__((ext_vector_type(8)));
typedef float f32x4 __attribute__((ext_vector_type(4)));
typedef _Float16 h16;
typedef h16 h16x2 __attribute__((ext_vector_type(2)));
typedef h16 h16x8 __attribute__((ext_vector_type(8)));
typedef unsigned short ushort_t;

#if __has_builtin(__builtin_amdgcn_fdot2)
#define HAS_FDOT2 1
#else
#define HAS_FDOT2 0
#endif

// HW packed f32->bf16 (RNE)
#define CVTPK(dst, a, b) asm("v_cvt_pk_bf16_f32 %0, %1, %2" : "=v"(dst) : "v"(a), "v"(b))

__device__ __forceinline__ unsigned short f2bf(float f) {
    union { float f; unsigned int i; } u; u.f = f;
    unsigned int r = u.i + 0x7FFFu + ((u.i >> 16) & 1u);
    return (unsigned short)(r >> 16);
}

// ---- DPP reductions (VALU pipe) ----
template<int CTRL>
__device__ __forceinline__ float dpp_add(float v) {
    int m = __builtin_amdgcn_update_dpp(0, __builtin_bit_cast(int, v), CTRL, 0xf, 0xf, false);
    return v + __builtin_bit_cast(float, m);
}
__device__ __forceinline__ float half_sum(float v) {
    v = dpp_add<0x111>(v); v = dpp_add<0x112>(v); v = dpp_add<0x114>(v);
    v = dpp_add<0x118>(v); v = dpp_add<0x142>(v);
    return v;
}
__device__ __forceinline__ float wave_sum(float v) {
    v = half_sum(v); v = dpp_add<0x143>(v);
    return v;
}
__device__ __forceinline__ float rlane(float v, int lane) {
    return __builtin_bit_cast(float, __builtin_amdgcn_readlane(__builtin_bit_cast(int, v), lane));
}

// ---------------- CSR build ----------------
__global__ void k_hist(const int* __restrict__ ei, int* __restrict__ deg) {
    int e = blockIdx.x * blockDim.x + threadIdx.x;
    if (e >= ET) return;
    int dst = (e < E_EDGES) ? ei[E_EDGES + e] : (e - E_EDGES);
    atomicAdd(&deg[dst], 1);
}

__global__ __launch_bounds__(1024) void k_scan(const int* __restrict__ deg,
                                               int* __restrict__ rowstart,
                                               int* __restrict__ cursor) {
    __shared__ int wsum[16];
    __shared__ int s_carry;
    int t = threadIdx.x, lane = t & 63, w = t >> 6;
    if (t == 0) s_carry = 0;
    __syncthreads();
    for (int base = 0; base < N_NODES; base += 4096) {
        int i0 = base + t * 4;
        int4 d = {0, 0, 0, 0};
        if (i0 + 3 < N_NODES) d = *(const int4*)(deg + i0);
        else {
            if (i0 + 0 < N_NODES) d.x = deg[i0 + 0];
            if (i0 + 1 < N_NODES) d.y = deg[i0 + 1];
            if (i0 + 2 < N_NODES) d.z = deg[i0 + 2];
            if (i0 + 3 < N_NODES) d.w = deg[i0 + 3];
        }
        int e1 = d.x, e2 = d.x + d.y, e3 = d.x + d.y + d.z;
        int tot = e3 + d.w;
        int sv = tot;
        for (int o = 1; o < 64; o <<= 1) { int u = __shfl_up(sv, o, 64); if (lane >= o) sv += u; }
        if (lane == 63) wsum[w] = sv;
        __syncthreads();
        if (w == 0) {
            int val = (lane < 16) ? wsum[lane] : 0;
            int s2 = val;
            for (int o = 1; o < 64; o <<= 1) { int u = __shfl_up(s2, o, 64); if (lane >= o) s2 += u; }
            if (lane < 16) wsum[lane] = s2 - val;
        }
        __syncthreads();
        int excl = s_carry + wsum[w] + (sv - tot);
        if (i0 + 3 < N_NODES) {
            int4 r = {excl, excl + e1, excl + e2, excl + e3};
            *(int4*)(rowstart + i0) = r;
            *(int4*)(cursor + i0) = r;
        } else {
            if (i0 + 0 < N_NODES) { rowstart[i0 + 0] = excl;      cursor[i0 + 0] = excl; }
            if (i0 + 1 < N_NODES) { rowstart[i0 + 1] = excl + e1; cursor[i0 + 1] = excl + e1; }
            if (i0 + 2 < N_NODES) { rowstart[i0 + 2] = excl + e2; cursor[i0 + 2] = excl + e2; }
            if (i0 + 3 < N_NODES) { rowstart[i0 + 3] = excl + e3; cursor[i0 + 3] = excl + e3; }
        }
        __syncthreads();
        if (t == 1023) s_carry += wsum[15] + sv;
        __syncthreads();
    }
    if (t == 0) rowstart[N_NODES] = ET;
}

// scatter: ONE thread per edge, max TLP (r16 lesson: never serialize atomics into a
// low-occupancy kernel — merged version was 85us at 2.9% VALUBusy).
__global__ void k_scatter(const int* __restrict__ ei, int* __restrict__ cursor,
                          int* __restrict__ csr_src) {
    int e = blockIdx.x * blockDim.x + threadIdx.x;
    if (e >= ET) return;
    int src, dst;
    if (e < E_EDGES) { src = ei[e]; dst = ei[E_EDGES + e]; }
    else             { src = dst = e - E_EDGES; }
    int pos = atomicAdd(&cursor[dst], 1);
    csr_src[pos] = src;
}

// ---------------- merged weight prep + deg zeroing ----------------
__global__ void k_wprep_all(const float* __restrict__ Wp,
                            const float* __restrict__ Wl,
                            const float* __restrict__ Wr,
                            unsigned short* __restrict__ wp_frag,
                            unsigned short* __restrict__ wc_frag,
                            int* __restrict__ deg) {
    int idx = blockIdx.x * blockDim.x + threadIdx.x;
    if (idx < N_NODES) deg[idx] = 0;
    if (idx < WPTOT) {
        int j = idx & 7, lane = (idx >> 3) & 63;
        int nt = (idx >> 9) % 6, ks = (idx >> 9) / 6;
        int k = ks * 32 + ((lane >> 4) << 3) + j;
        int col = nt * 16 + (lane & 15);
        wp_frag[idx] = f2bf(Wp[k * HID + col]);
    } else if (idx < WPTOT + 2 * WCTOT) {
        int L = (idx - WPTOT) / WCTOT;
        int id = (idx - WPTOT) % WCTOT;
        int j = id & 7, lane = (id >> 3) & 63;
        int nt = (id >> 9) % 12, ks = (id >> 9) / 12;
        int k = ks * 32 + ((lane >> 4) << 3) + j;
        int col = nt * 16 + (lane & 15);
        const float* W0 = Wl + (size_t)L * HID * HID;
        const float* W1 = Wr + (size_t)L * HID * HID;
        float v = (col < HID) ? W0[k * HID + col] : W1[k * HID + col - HID];
        wc_frag[(size_t)L * WCTOT + id] = f2bf(v);
    }
}

// ---------------- GEMM tile body (B staged in LDS; one 64-row tile per block) ----------------
// !PROJ writes xl in PADDED layout: row stride XLP=128 h16, head h at offset h*64
// (each per-head 96B gather then touches exactly ONE 128B cache line).
template<int K, int NT, bool PROJ>
__device__ __forceinline__ void gemm_tile(char* smem,
        const float* A, const ushort_t* Abf, const ushort_t* Bfrag,
        const float* bp, const float* g0, const float* b0,
        float* hout, ushort_t* hbout, h16* xl, h16* xr, int bid, int t) {
    constexpr int KS = K / 32;
    constexpr int NF = KS * NT;
    ushort_t* Blds = (ushort_t*)smem;
    int l = t & 63, w = t >> 6;
    int row0 = bid * 64 + w * 16;
    int arow = row0 + (l & 15);
    if (arow > N_NODES - 1) arow = N_NODES - 1;
    int kb = (l >> 4) * 8;
    bf16x8 a[KS];
    if constexpr (PROJ) {
        const float* ap = A + (long)arow * K + kb;
        #pragma unroll
        for (int ks = 0; ks < KS; ks++) {
            float4 f0 = *(const float4*)(ap + ks * 32);
            float4 f1 = *(const float4*)(ap + ks * 32 + 4);
            union { unsigned int u[4]; bf16x8 v; } cv;
            CVTPK(cv.u[0], f0.x, f0.y); CVTPK(cv.u[1], f0.z, f0.w);
            CVTPK(cv.u[2], f1.x, f1.y); CVTPK(cv.u[3], f1.z, f1.w);
            a[ks] = cv.v;
        }
    } else {
        const ushort_t* ap = Abf + (long)arow * K + kb;
        #pragma unroll
        for (int ks = 0; ks < KS; ks++) a[ks] = *(const bf16x8*)(ap + ks * 32);
    }
    // stage all B-frags
    #pragma unroll
    for (int i = 0; i < NF / 4; i++)
        ((float4*)Blds)[i * 256 + t] = ((const float4*)Bfrag)[i * 256 + t];
    __syncthreads();
    f32x4 acc[NT];
    #pragma unroll
    for (int nt = 0; nt < NT; nt++) acc[nt] = (f32x4){0.f, 0.f, 0.f, 0.f};
    #pragma unroll
    for (int nt = 0; nt < NT; nt++) {
        #pragma unroll
        for (int ks = 0; ks < KS; ks++) {
            bf16x8 b = *(const bf16x8*)(Blds + (((ks * NT + nt) * 64 + l) << 3));
            acc[nt] = __builtin_amdgcn_mfma_f32_16x16x32_bf16(a[ks], b, acc[nt], 0, 0, 0);
        }
    }
    int rg = l >> 4, cl = l & 15;
    if constexpr (PROJ) {
        float bpv[NT], g0v[NT], b0v[NT];
        #pragma unroll
        for (int nt = 0; nt < NT; nt++) {
            int col = nt * 16 + cl;
            bpv[nt] = bp[col]; g0v[nt] = g0[col]; b0v[nt] = b0[col];
        }
        #pragma unroll
        for (int r = 0; r < 4; r++) {
            float s = 0.f, sq = 0.f;
            #pragma unroll
            for (int nt = 0; nt < NT; nt++) {
                float v = acc[nt][r] + bpv[nt];
                acc[nt][r] = v; s += v; sq += v * v;
            }
            #pragma unroll
            for (int o = 1; o <= 8; o <<= 1) { s += __shfl_xor(s, o, 64); sq += __shfl_xor(sq, o, 64); }
            float mu = s / (float)HID;
            float var = sq / (float)HID - mu * mu;
            float rstd = rsqrtf(var + LN_EPS);
            int row = row0 + rg * 4 + r;
            if (row < N_NODES) {
                #pragma unroll
                for (int nt = 0; nt < NT; nt++) {
                    int col = nt * 16 + cl;
                    float y = fmaxf((acc[nt][r] - mu) * rstd * g0v[nt] + b0v[nt], 0.f);
                    hout[(long)row * HID + col] = y;
                    hbout[(long)row * HID + col] = f2bf(y);
                }
            }
        }
    } else {
        #pragma unroll
        for (int r = 0; r < 4; r++) {
            int row = row0 + rg * 4 + r;
            if (row < N_NODES) {
                #pragma unroll
                for (int nt = 0; nt < NT; nt++) {
                    int col = nt * 16 + cl;
                    h16 v = (h16)acc[nt][r];
                    if (col < HID) xl[(long)row * XLP + col + ((col >= CPH) ? 16 : 0)] = v;
                    else           xr[(long)row * HID + col - HID] = v;
                }
            }
        }
    }
}

// ---------------- input-projection GEMM (standalone) ----------------
__global__ __launch_bounds__(256) void k_proj(const float* __restrict__ x,
                                              const ushort_t* __restrict__ wp_frag,
                                              const float* __restrict__ bp,
                                              const float* __restrict__ g0,
                                              const float* __restrict__ b0,
                                              float* __restrict__ h,
                                              ushort_t* __restrict__ hb) {
    __shared__ __align__(16) char smem[WPTOT * 2];   // 24 KB B-stage
    gemm_tile<IN_DIM, 6, true>(smem, x, nullptr, wp_frag, bp, g0, b0,
                               h, hb, nullptr, nullptr, blockIdx.x, threadIdx.x);
}

// ---------------- per-layer transform GEMM ----------------
__global__ __launch_bounds__(256) void k_xfm(const ushort_t* __restrict__ hb,
                                             const ushort_t* __restrict__ wc_frag,
                                             h16* __restrict__ xl, h16* __restrict__ xr) {
    __shared__ __align__(16) char smem[WCTOT * 2];   // 36 KB B-stage
    gemm_tile<HID, 12, false>(smem, nullptr, hb, wc_frag, nullptr, nullptr, nullptr,
                              nullptr, nullptr, xl, xr, blockIdx.x, threadIdx.x);
}

// ---------------- fused: persistent waves; xl gathers from line-aligned padded rows ----------
// r19: xl row stride 256B, head hh at byte offset hh*128 -> each 96B per-head gather hits
// exactly one 128B line (was ~1.75 lines avg when rows were 192B unaligned). Per-edge line
// traffic 448->256B; FETCH predicted 87->~55MB.
__global__ __launch_bounds__(256) void k_node_fused(const int* __restrict__ rowstart,
                                                    const int* __restrict__ csr_src,
                                                    const h16* __restrict__ xl,
                                                    const h16* __restrict__ xr,
                                                    const float* __restrict__ att,
                                                    const float* __restrict__ gs,
                                                    const float* __restrict__ bs,
                                                    float* __restrict__ h,
                                                    ushort_t* __restrict__ hb,
                                                    float* __restrict__ out,
                                                    int write_out) {
    __shared__ float lds[4 * WTILE];
    int t = threadIdx.x, lane = t & 63, w = t >> 6;
    float* slds = lds + w * WTILE;
    float* pbuf = slds + PBASE;
    int j = lane & 31, hh = lane >> 5;
    bool jok = (j < CHUNK);
    int l = lane;
    int lc = (l < 48) ? l : 47;
    bool hi = (lc >= 24);
    bool act = (l < 48);

    const float* ar = att + hh * CPH;
    h16x8 attv[6];
    #pragma unroll
    for (int v = 0; v < 6; v++) {
        float4 t0 = *(const float4*)(ar + v * 8);
        float4 t1 = *(const float4*)(ar + v * 8 + 4);
        const float LG2E = 1.44269504088896f;     // fold exp->exp2 into att
        attv[v] = (h16x8){(h16)(t0.x * LG2E), (h16)(t0.y * LG2E), (h16)(t0.z * LG2E), (h16)(t0.w * LG2E),
                          (h16)(t1.x * LG2E), (h16)(t1.y * LG2E), (h16)(t1.z * LG2E), (h16)(t1.w * LG2E)};
    }

    for (int n = blockIdx.x * 4 + w; n < N_NODES; n += FBLK * 4) {
        int rs = rowstart[n], re = rowstart[n + 1];
        const h16x8* xrr = (const h16x8*)(xr + (long)n * HID + hh * CPH);
        h16x8 xrv[6];
        #pragma unroll
        for (int v = 0; v < 6; v++) xrv[v] = xrr[v];

        float Dl = 0.f;
        float2 acc = {0.f, 0.f};

        for (int base = rs; base < re; base += CHUNK) {
            int L = min(CHUNK, re - base);
            if (jok) {
                float p = 0.f;
                int srcj = csr_src[base + min(j, L - 1)];
                const h16x8* xlr = (const h16x8*)(xl + (long)srcj * XLP + hh * 64);
                float s0 = 0.f, s1 = 0.f;
#if !HAS_FDOT2
                h16x8 sacc = (h16x8)(h16)0.f;
#endif
                #pragma unroll
                for (int v = 0; v < 6; v++) {
                    h16x8 xa = xlr[v];
                    *(h16x8*)(slds + j * LROW + hh * 24 + v * 4) = xa;
                    h16x8 sum = xa + xrv[v];
                    h16x8 lk = __builtin_elementwise_max(sum, sum * (h16)NEG_SLOPE);
#if HAS_FDOT2
                    s0 = __builtin_amdgcn_fdot2(__builtin_shufflevector(lk, lk, 0, 1),
                                                __builtin_shufflevector(attv[v], attv[v], 0, 1), s0, false);
                    s1 = __builtin_amdgcn_fdot2(__builtin_shufflevector(lk, lk, 2, 3),
                                                __builtin_shufflevector(attv[v], attv[v], 2, 3), s1, false);
                    s0 = __builtin_amdgcn_fdot2(__builtin_shufflevector(lk, lk, 4, 5),
                                                __builtin_shufflevector(attv[v], attv[v], 4, 5), s0, false);
                    s1 = __builtin_amdgcn_fdot2(__builtin_shufflevector(lk, lk, 6, 7),
                                                __builtin_shufflevector(attv[v], attv[v], 6, 7), s1, false);
#else
                    sacc += lk * attv[v];
#endif
                }
#if !HAS_FDOT2
                {
                    h16x2 p0 = __builtin_shufflevector(sacc, sacc, 0, 1);
                    h16x2 p1 = __builtin_shufflevector(sacc, sacc, 2, 3);
                    h16x2 p2 = __builtin_shufflevector(sacc, sacc, 4, 5);
                    h16x2 p3 = __builtin_shufflevector(sacc, sacc, 6, 7);
                    h16x2 q = (p0 + p1) + (p2 + p3);
                    s0 = (float)q.x + (float)q.y; s1 = 0.f;
                }
#endif
                if (j < L) { p = exp2f(s0 + s1); Dl += p; }
                pbuf[hh * CHUNK + j] = p;
            }
            __builtin_amdgcn_s_setprio(1);
            const float* prow = pbuf + (hi ? CHUNK : 0);
            #pragma unroll
            for (int i4 = 0; i4 < CHUNK / 4; i4++) {
                if (i4 * 4 >= L) break;
                float4 pv = *(const float4*)(prow + i4 * 4);
                #pragma unroll
                for (int k = 0; k < 4; k++) {
                    h16x2 hv = ((const h16x2*)(slds + (i4 * 4 + k) * LROW))[lc];
                    float pk = ((const float*)&pv)[k];
                    acc.x += pk * (float)hv.x;
                    acc.y += pk * (float)hv.y;
                }
            }
            __builtin_amdgcn_s_setprio(0);
        }
        float sh = half_sum(Dl);
        float D0 = rlane(sh, 31), D1 = rlane(sh, 63);
        float myD = hi ? D1 : D0;
        float oa = acc.x / myD, ob = acc.y / myD;
        float oaz = act ? oa : 0.f, obz = act ? ob : 0.f;
        float s1r = wave_sum(oaz + obz);
        float s2r = wave_sum(oaz * oaz + obz * obz);
        float mu = rlane(s1r, 63) / (float)HID;
        float var = rlane(s2r, 63) / (float)HID - mu * mu;
        float rstd = rsqrtf(var + LN_EPS);
        if (act) {
            long baseo = (long)n * HID + 2 * l;
            float2 g = *(const float2*)(gs + 2 * l);
            float2 b = *(const float2*)(bs + 2 * l);
            float y0 = (oaz - mu) * rstd * g.x + b.x;
            float y1 = (obz - mu) * rstd * g.y + b.y;
            float hn0 = (y0 > 0.f) ? y0 : expm1f(y0);
            float hn1 = (y1 > 0.f) ? y1 : expm1f(y1);
            float2 hold = *(float2*)(h + baseo);
            float2 hv = {hold.x + hn0, hold.y + hn1};
            if (write_out) {
                *(float2*)(out + baseo) = hv;        // final layer: h store is dead, skip it
            } else {
                *(float2*)(h + baseo) = hv;
                unsigned int hp;
                CVTPK(hp, hv.x, hv.y);
                *(unsigned int*)(hb + baseo) = hp;
            }
        }
    }
}

extern "C" void kernel_launch(void* const* d_in, const int* in_sizes, int n_in,
                              void* d_out, int out_size, void* d_ws, size_t ws_size,
                              hipStream_t stream) {
    const float* x   = (const float*)d_in[0];
    const int*   ei  = (const int*)d_in[1];
    const float* Wp  = (const float*)d_in[2];
    const float* bp  = (const float*)d_in[3];
    const float* g0  = (const float*)d_in[4];
    const float* b0  = (const float*)d_in[5];
    const float* Wl  = (const float*)d_in[6];
    const float* Wr  = (const float*)d_in[7];
    const float* att = (const float*)d_in[8];
    const float* gs  = (const float*)d_in[9];
    const float* bs  = (const float*)d_in[10];
    float* out = (float*)d_out;

    char* wsp = (char*)d_ws;
    size_t off = 0;
    auto alloc = [&](size_t bytes) { void* p = wsp + off; off += (bytes + 255) / 256 * 256; return p; };
    float*    h       = (float*)   alloc((size_t)N_NODES * HID * 4);
    ushort_t* hb      = (ushort_t*)alloc((size_t)N_NODES * HID * 2);
    h16*      xl      = (h16*)     alloc((size_t)N_NODES * XLP * 2);   // padded: 256B/row
    h16*      xr      = (h16*)     alloc((size_t)N_NODES * HID * 2);
    int*      deg     = (int*)     alloc((size_t)N_NODES * 4);
    int*      rowst   = (int*)     alloc((size_t)(N_NODES + 1) * 4);
    int*      cursor  = (int*)     alloc((size_t)N_NODES * 4);
    int*      csr_src = (int*)     alloc((size_t)ET * 4);
    ushort_t* wp_frag = (ushort_t*)alloc((size_t)WPTOT * 2);
    ushort_t* wc_frag = (ushort_t*)alloc((size_t)2 * WCTOT * 2);

    k_wprep_all<<<(N_NODES + 255) / 256, 256, 0, stream>>>(Wp, Wl, Wr, wp_frag, wc_frag, deg);
    k_hist<<<(ET + 255) / 256, 256, 0, stream>>>(ei, deg);
    k_scan<<<1, 1024, 0, stream>>>(deg, rowst, cursor);
    k_scatter<<<(ET + 255) / 256, 256, 0, stream>>>(ei, cursor, csr_src);
    k_proj<<<GBLK, 256, 0, stream>>>(x, wp_frag, bp, g0, b0, h, hb);
    for (int L = 0; L < 2; L++) {
        k_xfm<<<GBLK, 256, 0, stream>>>(hb, wc_frag + (size_t)L * WCTOT, xl, xr);
        k_node_fused<<<FBLK, 256, 0, stream>>>(rowst, csr_src, xl, xr,
                                               att + (size_t)L * HEADS * CPH,
                                               gs + (size_t)L * HID, bs + (size_t)L * HID,
                                               h, hb, out, (L == 1) ? 1 : 0);
    }
}

// Round 20
// 261.552 us; speedup vs baseline: 1.0206x; 1.0206x over previous
//
#include <hip/hip_runtime.h>
#include <hip/hip_bf16.h>

#define N_NODES 50000
#define E_EDGES 800000
#define ET (E_EDGES + N_NODES)   /* 850000 edges incl self loops */
#define IN_DIM 128
#define HID 96
#define HEADS 2
#define CPH 48
#define NEG_SLOPE 0.2f
#define LN_EPS 1e-5f
#define CHUNK 24                 /* edges per softmax/agg chunk */
#define LROW 50                  /* LDS dwords per staged edge row */
#define PBASE (CHUNK * LROW)
#define WTILE (PBASE + 2 * CHUNK)/* per-wave LDS dwords: 1248 -> 4992 B */
#define FBLK 2048                /* persistent-wave grid for k_node_fused */
#define GBLK ((N_NODES + 63) / 64)
#define WPTOT (IN_DIM * HID)     /* 12288 */
#define WCTOT (HID * 2 * HID)    /* 18432 per layer */

typedef __hip_bfloat16 bf16;
typedef short bf16x8 __attribute__((ext_vector_type(8)));
typedef float f32x4 __attribute__((ext_vector_type(4)));
typedef _Float16 h16;
typedef h16 h16x2 __attribute__((ext_vector_type(2)));
typedef h16 h16x8 __attribute__((ext_vector_type(8)));
typedef unsigned short ushort_t;

#if __has_builtin(__builtin_amdgcn_fdot2)
#define HAS_FDOT2 1
#else
#define HAS_FDOT2 0
#endif

// HW packed f32->bf16 (RNE)
#define CVTPK(dst, a, b) asm("v_cvt_pk_bf16_f32 %0, %1, %2" : "=v"(dst) : "v"(a), "v"(b))

__device__ __forceinline__ unsigned short f2bf(float f) {
    union { float f; unsigned int i; } u; u.f = f;
    unsigned int r = u.i + 0x7FFFu + ((u.i >> 16) & 1u);
    return (unsigned short)(r >> 16);
}

// ---- DPP reductions (VALU pipe) ----
template<int CTRL>
__device__ __forceinline__ float dpp_add(float v) {
    int m = __builtin_amdgcn_update_dpp(0, __builtin_bit_cast(int, v), CTRL, 0xf, 0xf, false);
    return v + __builtin_bit_cast(float, m);
}
__device__ __forceinline__ float half_sum(float v) {
    v = dpp_add<0x111>(v); v = dpp_add<0x112>(v); v = dpp_add<0x114>(v);
    v = dpp_add<0x118>(v); v = dpp_add<0x142>(v);
    return v;
}
__device__ __forceinline__ float wave_sum(float v) {
    v = half_sum(v); v = dpp_add<0x143>(v);
    return v;
}
__device__ __forceinline__ float rlane(float v, int lane) {
    return __builtin_bit_cast(float, __builtin_amdgcn_readlane(__builtin_bit_cast(int, v), lane));
}

// ---------------- CSR build ----------------
__global__ void k_hist(const int* __restrict__ ei, int* __restrict__ deg) {
    int e = blockIdx.x * blockDim.x + threadIdx.x;
    if (e >= ET) return;
    int dst = (e < E_EDGES) ? ei[E_EDGES + e] : (e - E_EDGES);
    atomicAdd(&deg[dst], 1);
}

__global__ __launch_bounds__(1024) void k_scan(const int* __restrict__ deg,
                                               int* __restrict__ rowstart,
                                               int* __restrict__ cursor) {
    __shared__ int wsum[16];
    __shared__ int s_carry;
    int t = threadIdx.x, lane = t & 63, w = t >> 6;
    if (t == 0) s_carry = 0;
    __syncthreads();
    for (int base = 0; base < N_NODES; base += 4096) {
        int i0 = base + t * 4;
        int4 d = {0, 0, 0, 0};
        if (i0 + 3 < N_NODES) d = *(const int4*)(deg + i0);
        else {
            if (i0 + 0 < N_NODES) d.x = deg[i0 + 0];
            if (i0 + 1 < N_NODES) d.y = deg[i0 + 1];
            if (i0 + 2 < N_NODES) d.z = deg[i0 + 2];
            if (i0 + 3 < N_NODES) d.w = deg[i0 + 3];
        }
        int e1 = d.x, e2 = d.x + d.y, e3 = d.x + d.y + d.z;
        int tot = e3 + d.w;
        int sv = tot;
        for (int o = 1; o < 64; o <<= 1) { int u = __shfl_up(sv, o, 64); if (lane >= o) sv += u; }
        if (lane == 63) wsum[w] = sv;
        __syncthreads();
        if (w == 0) {
            int val = (lane < 16) ? wsum[lane] : 0;
            int s2 = val;
            for (int o = 1; o < 64; o <<= 1) { int u = __shfl_up(s2, o, 64); if (lane >= o) s2 += u; }
            if (lane < 16) wsum[lane] = s2 - val;
        }
        __syncthreads();
        int excl = s_carry + wsum[w] + (sv - tot);
        if (i0 + 3 < N_NODES) {
            int4 r = {excl, excl + e1, excl + e2, excl + e3};
            *(int4*)(rowstart + i0) = r;
            *(int4*)(cursor + i0) = r;
        } else {
            if (i0 + 0 < N_NODES) { rowstart[i0 + 0] = excl;      cursor[i0 + 0] = excl; }
            if (i0 + 1 < N_NODES) { rowstart[i0 + 1] = excl + e1; cursor[i0 + 1] = excl + e1; }
            if (i0 + 2 < N_NODES) { rowstart[i0 + 2] = excl + e2; cursor[i0 + 2] = excl + e2; }
            if (i0 + 3 < N_NODES) { rowstart[i0 + 3] = excl + e3; cursor[i0 + 3] = excl + e3; }
        }
        __syncthreads();
        if (t == 1023) s_carry += wsum[15] + sv;
        __syncthreads();
    }
    if (t == 0) rowstart[N_NODES] = ET;
}

// scatter: ONE thread per edge, max TLP (r16 lesson: never serialize atomics into a
// low-occupancy kernel — merged version was 85us at 2.9% VALUBusy).
__global__ void k_scatter(const int* __restrict__ ei, int* __restrict__ cursor,
                          int* __restrict__ csr_src) {
    int e = blockIdx.x * blockDim.x + threadIdx.x;
    if (e >= ET) return;
    int src, dst;
    if (e < E_EDGES) { src = ei[e]; dst = ei[E_EDGES + e]; }
    else             { src = dst = e - E_EDGES; }
    int pos = atomicAdd(&cursor[dst], 1);
    csr_src[pos] = src;
}

// ---------------- merged weight prep + deg zeroing ----------------
__global__ void k_wprep_all(const float* __restrict__ Wp,
                            const float* __restrict__ Wl,
                            const float* __restrict__ Wr,
                            unsigned short* __restrict__ wp_frag,
                            unsigned short* __restrict__ wc_frag,
                            int* __restrict__ deg) {
    int idx = blockIdx.x * blockDim.x + threadIdx.x;
    if (idx < N_NODES) deg[idx] = 0;
    if (idx < WPTOT) {
        int j = idx & 7, lane = (idx >> 3) & 63;
        int nt = (idx >> 9) % 6, ks = (idx >> 9) / 6;
        int k = ks * 32 + ((lane >> 4) << 3) + j;
        int col = nt * 16 + (lane & 15);
        wp_frag[idx] = f2bf(Wp[k * HID + col]);
    } else if (idx < WPTOT + 2 * WCTOT) {
        int L = (idx - WPTOT) / WCTOT;
        int id = (idx - WPTOT) % WCTOT;
        int j = id & 7, lane = (id >> 3) & 63;
        int nt = (id >> 9) % 12, ks = (id >> 9) / 12;
        int k = ks * 32 + ((lane >> 4) << 3) + j;
        int col = nt * 16 + (lane & 15);
        const float* W0 = Wl + (size_t)L * HID * HID;
        const float* W1 = Wr + (size_t)L * HID * HID;
        float v = (col < HID) ? W0[k * HID + col] : W1[k * HID + col - HID];
        wc_frag[(size_t)L * WCTOT + id] = f2bf(v);
    }
}

// ---------------- GEMM tile body (B staged in LDS; one 64-row tile per block) ----------------
template<int K, int NT, bool PROJ>
__device__ __forceinline__ void gemm_tile(char* smem,
        const float* A, const ushort_t* Abf, const ushort_t* Bfrag,
        const float* bp, const float* g0, const float* b0,
        float* hout, ushort_t* hbout, h16* xl, h16* xr, int bid, int t) {
    constexpr int KS = K / 32;
    constexpr int NF = KS * NT;
    ushort_t* Blds = (ushort_t*)smem;
    int l = t & 63, w = t >> 6;
    int row0 = bid * 64 + w * 16;
    int arow = row0 + (l & 15);
    if (arow > N_NODES - 1) arow = N_NODES - 1;
    int kb = (l >> 4) * 8;
    bf16x8 a[KS];
    if constexpr (PROJ) {
        const float* ap = A + (long)arow * K + kb;
        #pragma unroll
        for (int ks = 0; ks < KS; ks++) {
            float4 f0 = *(const float4*)(ap + ks * 32);
            float4 f1 = *(const float4*)(ap + ks * 32 + 4);
            union { unsigned int u[4]; bf16x8 v; } cv;
            CVTPK(cv.u[0], f0.x, f0.y); CVTPK(cv.u[1], f0.z, f0.w);
            CVTPK(cv.u[2], f1.x, f1.y); CVTPK(cv.u[3], f1.z, f1.w);
            a[ks] = cv.v;
        }
    } else {
        const ushort_t* ap = Abf + (long)arow * K + kb;
        #pragma unroll
        for (int ks = 0; ks < KS; ks++) a[ks] = *(const bf16x8*)(ap + ks * 32);
    }
    // stage all B-frags
    #pragma unroll
    for (int i = 0; i < NF / 4; i++)
        ((float4*)Blds)[i * 256 + t] = ((const float4*)Bfrag)[i * 256 + t];
    __syncthreads();
    f32x4 acc[NT];
    #pragma unroll
    for (int nt = 0; nt < NT; nt++) acc[nt] = (f32x4){0.f, 0.f, 0.f, 0.f};
    #pragma unroll
    for (int nt = 0; nt < NT; nt++) {
        #pragma unroll
        for (int ks = 0; ks < KS; ks++) {
            bf16x8 b = *(const bf16x8*)(Blds + (((ks * NT + nt) * 64 + l) << 3));
            acc[nt] = __builtin_amdgcn_mfma_f32_16x16x32_bf16(a[ks], b, acc[nt], 0, 0, 0);
        }
    }
    int rg = l >> 4, cl = l & 15;
    if constexpr (PROJ) {
        float bpv[NT], g0v[NT], b0v[NT];
        #pragma unroll
        for (int nt = 0; nt < NT; nt++) {
            int col = nt * 16 + cl;
            bpv[nt] = bp[col]; g0v[nt] = g0[col]; b0v[nt] = b0[col];
        }
        #pragma unroll
        for (int r = 0; r < 4; r++) {
            float s = 0.f, sq = 0.f;
            #pragma unroll
            for (int nt = 0; nt < NT; nt++) {
                float v = acc[nt][r] + bpv[nt];
                acc[nt][r] = v; s += v; sq += v * v;
            }
            #pragma unroll
            for (int o = 1; o <= 8; o <<= 1) { s += __shfl_xor(s, o, 64); sq += __shfl_xor(sq, o, 64); }
            float mu = s / (float)HID;
            float var = sq / (float)HID - mu * mu;
            float rstd = rsqrtf(var + LN_EPS);
            int row = row0 + rg * 4 + r;
            if (row < N_NODES) {
                #pragma unroll
                for (int nt = 0; nt < NT; nt++) {
                    int col = nt * 16 + cl;
                    float y = fmaxf((acc[nt][r] - mu) * rstd * g0v[nt] + b0v[nt], 0.f);
                    hout[(long)row * HID + col] = y;
                    hbout[(long)row * HID + col] = f2bf(y);
                }
            }
        }
    } else {
        #pragma unroll
        for (int r = 0; r < 4; r++) {
            int row = row0 + rg * 4 + r;
            if (row < N_NODES) {
                #pragma unroll
                for (int nt = 0; nt < NT; nt++) {
                    int col = nt * 16 + cl;
                    h16 v = (h16)acc[nt][r];
                    if (col < HID) xl[(long)row * HID + col] = v;
                    else           xr[(long)row * HID + col - HID] = v;
                }
            }
        }
    }
}

// ---------------- input-projection GEMM (standalone) ----------------
__global__ __launch_bounds__(256) void k_proj(const float* __restrict__ x,
                                              const ushort_t* __restrict__ wp_frag,
                                              const float* __restrict__ bp,
                                              const float* __restrict__ g0,
                                              const float* __restrict__ b0,
                                              float* __restrict__ h,
                                              ushort_t* __restrict__ hb) {
    __shared__ __align__(16) char smem[WPTOT * 2];   // 24 KB B-stage
    gemm_tile<IN_DIM, 6, true>(smem, x, nullptr, wp_frag, bp, g0, b0,
                               h, hb, nullptr, nullptr, blockIdx.x, threadIdx.x);
}

// ---------------- per-layer transform GEMM ----------------
__global__ __launch_bounds__(256) void k_xfm(const ushort_t* __restrict__ hb,
                                             const ushort_t* __restrict__ wc_frag,
                                             h16* __restrict__ xl, h16* __restrict__ xr) {
    __shared__ __align__(16) char smem[WCTOT * 2];   // 36 KB B-stage
    gemm_tile<HID, 12, false>(smem, nullptr, hb, wc_frag, nullptr, nullptr, nullptr,
                              nullptr, nullptr, xl, xr, blockIdx.x, threadIdx.x);
}

// ---------------- fused: persistent waves (best measured config, r18 = 262.39 us) ----------
// xl rows COMPACT (192B): both head-halves read the same row together -> exactly 2 lines/edge;
// r19's 256B padding kept traffic at 2 lines but grew the footprint 33% -> L2 hit down, FETCH up.
// Gather is latency x concurrency bound at the ~12 waves/CU occupancy plateau (r5/r6/r10/r12/r15).
__global__ __launch_bounds__(256) void k_node_fused(const int* __restrict__ rowstart,
                                                    const int* __restrict__ csr_src,
                                                    const h16* __restrict__ xl,
                                                    const h16* __restrict__ xr,
                                                    const float* __restrict__ att,
                                                    const float* __restrict__ gs,
                                                    const float* __restrict__ bs,
                                                    float* __restrict__ h,
                                                    ushort_t* __restrict__ hb,
                                                    float* __restrict__ out,
                                                    int write_out) {
    __shared__ float lds[4 * WTILE];
    int t = threadIdx.x, lane = t & 63, w = t >> 6;
    float* slds = lds + w * WTILE;
    float* pbuf = slds + PBASE;
    int j = lane & 31, hh = lane >> 5;
    bool jok = (j < CHUNK);
    int l = lane;
    int lc = (l < 48) ? l : 47;
    bool hi = (lc >= 24);
    bool act = (l < 48);

    const float* ar = att + hh * CPH;
    h16x8 attv[6];
    #pragma unroll
    for (int v = 0; v < 6; v++) {
        float4 t0 = *(const float4*)(ar + v * 8);
        float4 t1 = *(const float4*)(ar + v * 8 + 4);
        const float LG2E = 1.44269504088896f;     // fold exp->exp2 into att
        attv[v] = (h16x8){(h16)(t0.x * LG2E), (h16)(t0.y * LG2E), (h16)(t0.z * LG2E), (h16)(t0.w * LG2E),
                          (h16)(t1.x * LG2E), (h16)(t1.y * LG2E), (h16)(t1.z * LG2E), (h16)(t1.w * LG2E)};
    }

    for (int n = blockIdx.x * 4 + w; n < N_NODES; n += FBLK * 4) {
        int rs = rowstart[n], re = rowstart[n + 1];
        const h16x8* xrr = (const h16x8*)(xr + (long)n * HID + hh * CPH);
        h16x8 xrv[6];
        #pragma unroll
        for (int v = 0; v < 6; v++) xrv[v] = xrr[v];

        float Dl = 0.f;
        float2 acc = {0.f, 0.f};

        for (int base = rs; base < re; base += CHUNK) {
            int L = min(CHUNK, re - base);
            if (jok) {
                float p = 0.f;
                int srcj = csr_src[base + min(j, L - 1)];
                const h16x8* xlr = (const h16x8*)(xl + (long)srcj * HID + hh * CPH);
                float s0 = 0.f, s1 = 0.f;
#if !HAS_FDOT2
                h16x8 sacc = (h16x8)(h16)0.f;
#endif
                #pragma unroll
                for (int v = 0; v < 6; v++) {
                    h16x8 xa = xlr[v];
                    *(h16x8*)(slds + j * LROW + hh * 24 + v * 4) = xa;
                    h16x8 sum = xa + xrv[v];
                    h16x8 lk = __builtin_elementwise_max(sum, sum * (h16)NEG_SLOPE);
#if HAS_FDOT2
                    s0 = __builtin_amdgcn_fdot2(__builtin_shufflevector(lk, lk, 0, 1),
                                                __builtin_shufflevector(attv[v], attv[v], 0, 1), s0, false);
                    s1 = __builtin_amdgcn_fdot2(__builtin_shufflevector(lk, lk, 2, 3),
                                                __builtin_shufflevector(attv[v], attv[v], 2, 3), s1, false);
                    s0 = __builtin_amdgcn_fdot2(__builtin_shufflevector(lk, lk, 4, 5),
                                                __builtin_shufflevector(attv[v], attv[v], 4, 5), s0, false);
                    s1 = __builtin_amdgcn_fdot2(__builtin_shufflevector(lk, lk, 6, 7),
                                                __builtin_shufflevector(attv[v], attv[v], 6, 7), s1, false);
#else
                    sacc += lk * attv[v];
#endif
                }
#if !HAS_FDOT2
                {
                    h16x2 p0 = __builtin_shufflevector(sacc, sacc, 0, 1);
                    h16x2 p1 = __builtin_shufflevector(sacc, sacc, 2, 3);
                    h16x2 p2 = __builtin_shufflevector(sacc, sacc, 4, 5);
                    h16x2 p3 = __builtin_shufflevector(sacc, sacc, 6, 7);
                    h16x2 q = (p0 + p1) + (p2 + p3);
                    s0 = (float)q.x + (float)q.y; s1 = 0.f;
                }
#endif
                if (j < L) { p = exp2f(s0 + s1); Dl += p; }
                pbuf[hh * CHUNK + j] = p;
            }
            __builtin_amdgcn_s_setprio(1);
            const float* prow = pbuf + (hi ? CHUNK : 0);
            #pragma unroll
            for (int i4 = 0; i4 < CHUNK / 4; i4++) {
                if (i4 * 4 >= L) break;
                float4 pv = *(const float4*)(prow + i4 * 4);
                #pragma unroll
                for (int k = 0; k < 4; k++) {
                    h16x2 hv = ((const h16x2*)(slds + (i4 * 4 + k) * LROW))[lc];
                    float pk = ((const float*)&pv)[k];
                    acc.x += pk * (float)hv.x;
                    acc.y += pk * (float)hv.y;
                }
            }
            __builtin_amdgcn_s_setprio(0);
        }
        float sh = half_sum(Dl);
        float D0 = rlane(sh, 31), D1 = rlane(sh, 63);
        float myD = hi ? D1 : D0;
        float oa = acc.x / myD, ob = acc.y / myD;
        float oaz = act ? oa : 0.f, obz = act ? ob : 0.f;
        float s1r = wave_sum(oaz + obz);
        float s2r = wave_sum(oaz * oaz + obz * obz);
        float mu = rlane(s1r, 63) / (float)HID;
        float var = rlane(s2r, 63) / (float)HID - mu * mu;
        float rstd = rsqrtf(var + LN_EPS);
        if (act) {
            long baseo = (long)n * HID + 2 * l;
            float2 g = *(const float2*)(gs + 2 * l);
            float2 b = *(const float2*)(bs + 2 * l);
            float y0 = (oaz - mu) * rstd * g.x + b.x;
            float y1 = (obz - mu) * rstd * g.y + b.y;
            float hn0 = (y0 > 0.f) ? y0 : expm1f(y0);
            float hn1 = (y1 > 0.f) ? y1 : expm1f(y1);
            float2 hold = *(float2*)(h + baseo);
            float2 hv = {hold.x + hn0, hold.y + hn1};
            if (write_out) {
                *(float2*)(out + baseo) = hv;        // final layer: h store is dead, skip it
            } else {
                *(float2*)(h + baseo) = hv;
                unsigned int hp;
                CVTPK(hp, hv.x, hv.y);
                *(unsigned int*)(hb + baseo) = hp;
            }
        }
    }
}

extern "C" void kernel_launch(void* const* d_in, const int* in_sizes, int n_in,
                              void* d_out, int out_size, void* d_ws, size_t ws_size,
                              hipStream_t stream) {
    const float* x   = (const float*)d_in[0];
    const int*   ei  = (const int*)d_in[1];
    const float* Wp  = (const float*)d_in[2];
    const float* bp  = (const float*)d_in[3];
    const float* g0  = (const float*)d_in[4];
    const float* b0  = (const float*)d_in[5];
    const float* Wl  = (const float*)d_in[6];
    const float* Wr  = (const float*)d_in[7];
    const float* att = (const float*)d_in[8];
    const float* gs  = (const float*)d_in[9];
    const float* bs  = (const float*)d_in[10];
    float* out = (float*)d_out;

    char* wsp = (char*)d_ws;
    size_t off = 0;
    auto alloc = [&](size_t bytes) { void* p = wsp + off; off += (bytes + 255) / 256 * 256; return p; };
    float*    h       = (float*)   alloc((size_t)N_NODES * HID * 4);
    ushort_t* hb      = (ushort_t*)alloc((size_t)N_NODES * HID * 2);
    h16*      xl      = (h16*)     alloc((size_t)N_NODES * HID * 2);
    h16*      xr      = (h16*)     alloc((size_t)N_NODES * HID * 2);
    int*      deg     = (int*)     alloc((size_t)N_NODES * 4);
    int*      rowst   = (int*)     alloc((size_t)(N_NODES + 1) * 4);
    int*      cursor  = (int*)     alloc((size_t)N_NODES * 4);
    int*      csr_src = (int*)     alloc((size_t)ET * 4);
    ushort_t* wp_frag = (ushort_t*)alloc((size_t)WPTOT * 2);
    ushort_t* wc_frag = (ushort_t*)alloc((size_t)2 * WCTOT * 2);

    k_wprep_all<<<(N_NODES + 255) / 256, 256, 0, stream>>>(Wp, Wl, Wr, wp_frag, wc_frag, deg);
    k_hist<<<(ET + 255) / 256, 256, 0, stream>>>(ei, deg);
    k_scan<<<1, 1024, 0, stream>>>(deg, rowst, cursor);
    k_scatter<<<(ET + 255) / 256, 256, 0, stream>>>(ei, cursor, csr_src);
    k_proj<<<GBLK, 256, 0, stream>>>(x, wp_frag, bp, g0, b0, h, hb);
    for (int L = 0; L < 2; L++) {
        k_xfm<<<GBLK, 256, 0, stream>>>(hb, wc_frag + (size_t)L * WCTOT, xl, xr);
        k_node_fused<<<FBLK, 256, 0, stream>>>(rowst, csr_src, xl, xr,
                                               att + (size_t)L * HEADS * CPH,
                                               gs + (size_t)L * HID, bs + (size_t)L * HID,
                                               h, hb, out, (L == 1) ? 1 : 0);
    }
}